// Round 1
// baseline (221.784 us; speedup 1.0000x reference)
//
#include <hip/hip_runtime.h>

#define B_ 8
#define DIM_ 512
#define HEADS_ 8
#define HD_ 64
#define HW_ 1024
#define L_ 77
#define LP_ 80
#define CTX_ 768
#define KV_ 1101
#define KVP_ 1120
#define LOG2E 1.4426950408889634f

typedef __attribute__((ext_vector_type(8))) short bf16x8;
typedef __attribute__((ext_vector_type(4))) float f32x4;
typedef __attribute__((ext_vector_type(4))) unsigned short u16x4;

__device__ __forceinline__ unsigned short f2bf(float f) {
  union { float f; unsigned int u; } c; c.f = f;
  unsigned int u = c.u;
  return (unsigned short)((u + 0x7fffu + ((u >> 16) & 1u)) >> 16);
}
__device__ __forceinline__ float bf2f(unsigned short h) {
  union { unsigned int u; float f; } c; c.u = ((unsigned int)h) << 16;
  return c.f;
}

#define GLD_LDS16(gsrc, ldst) \
  __builtin_amdgcn_global_load_lds((const __attribute__((address_space(1))) void*)(gsrc), \
                                   (__attribute__((address_space(3))) void*)(ldst), 16, 0, 0)

// ---------------- converts ----------------
__global__ __launch_bounds__(256) void conv_bf16_k(const float* __restrict__ src,
                                                   unsigned short* __restrict__ dst, int n4) {
  int i = blockIdx.x * 256 + threadIdx.x;
  if (i >= n4) return;
  float4 v = *(const float4*)(src + (size_t)i * 4);
  u16x4 o;
  o[0] = f2bf(v.x); o[1] = f2bf(v.y); o[2] = f2bf(v.z); o[3] = f2bf(v.w);
  *(u16x4*)(dst + (size_t)i * 4) = o;
}

__global__ __launch_bounds__(256) void conv_ctx_k(const float* __restrict__ ctx,
                                                  unsigned short* __restrict__ dst) {
  int i = blockIdx.x * 256 + threadIdx.x;
  int total4 = B_ * LP_ * CTX_ / 4;
  if (i >= total4) return;
  int idx = i * 4;
  int b = idx / (LP_ * CTX_);
  int rem = idx - b * (LP_ * CTX_);
  int l = rem / CTX_;
  int c = rem - l * CTX_;
  float4 v = make_float4(0.f, 0.f, 0.f, 0.f);
  if (l < L_) v = *(const float4*)&ctx[((size_t)b * L_ + l) * CTX_ + c];
  u16x4 o;
  o[0] = f2bf(v.x); o[1] = f2bf(v.y); o[2] = f2bf(v.z); o[3] = f2bf(v.w);
  *(u16x4*)(dst + idx) = o;
}

// zero the KV pad rows (1101..1119) so 0xAA poison can't reach the PV MFMA
__global__ __launch_bounds__(256) void pad_zero_k(unsigned short* __restrict__ k_s,
                                                  unsigned short* __restrict__ vT) {
  int i = blockIdx.x * 256 + threadIdx.x;
  const int total = 64 * 19 * 64;
  if (i >= total) return;
  int bh = i / (19 * 64);
  int rem = i - bh * (19 * 64);
  int row = KV_ + rem / 64;
  int d = rem & 63;
  k_s[((size_t)bh * KVP_ + row) * HD_ + d] = 0;
  vT[((size_t)bh * HD_ + d) * KVP_ + row] = 0;
}

// ---------------- groupnorm (fused stats+normalize+transpose) ----------------
__global__ __launch_bounds__(256) void gnorm_k(const float* __restrict__ x,
                                               const float* __restrict__ gamma,
                                               const float* __restrict__ beta,
                                               unsigned short* __restrict__ xn_t) {
  __shared__ unsigned short xs[16][1032];
  __shared__ float red[8];
  const int tid = threadIdx.x;
  const int b = blockIdx.x >> 5, g = blockIdx.x & 31;
  const float* xp = x + ((size_t)b * DIM_ + g * 16) * HW_;
  float sum = 0.f, ssq = 0.f;
#pragma unroll
  for (int i = 0; i < 16; ++i) {
    float4 v = *(const float4*)&xp[i * HW_ + tid * 4];
    sum += v.x + v.y + v.z + v.w;
    ssq += v.x * v.x + v.y * v.y + v.z * v.z + v.w * v.w;
    xs[i][tid * 4 + 0] = f2bf(v.x);
    xs[i][tid * 4 + 1] = f2bf(v.y);
    xs[i][tid * 4 + 2] = f2bf(v.z);
    xs[i][tid * 4 + 3] = f2bf(v.w);
  }
#pragma unroll
  for (int off = 32; off >= 1; off >>= 1) {
    sum += __shfl_xor(sum, off, 64);
    ssq += __shfl_xor(ssq, off, 64);
  }
  if ((tid & 63) == 0) { red[(tid >> 6) * 2] = sum; red[(tid >> 6) * 2 + 1] = ssq; }
  __syncthreads();
  sum = red[0] + red[2] + red[4] + red[6];
  ssq = red[1] + red[3] + red[5] + red[7];
  float mu = sum * (1.f / 16384.f);
  float rstd = rsqrtf(ssq * (1.f / 16384.f) - mu * mu + 1e-5f);
  float a[16], c[16];
#pragma unroll
  for (int ci = 0; ci < 16; ++ci) {
    float gm = gamma[g * 16 + ci], bt = beta[g * 16 + ci];
    a[ci] = rstd * gm;
    c[ci] = bt - mu * rstd * gm;
  }
#pragma unroll
  for (int t = 0; t < 4; ++t) {
    int hw = tid + t * 256;
    unsigned short tmp[16];
#pragma unroll
    for (int ci = 0; ci < 16; ++ci)
      tmp[ci] = f2bf(bf2f(xs[ci][hw]) * a[ci] + c[ci]);
    unsigned int w[8];
#pragma unroll
    for (int j = 0; j < 8; ++j) w[j] = (unsigned int)tmp[2 * j] | ((unsigned int)tmp[2 * j + 1] << 16);
    unsigned short* dptr = &xn_t[((size_t)b * HW_ + hw) * DIM_ + g * 16];
    *(uint4*)dptr = make_uint4(w[0], w[1], w[2], w[3]);
    *(uint4*)(dptr + 8) = make_uint4(w[4], w[5], w[6], w[7]);
  }
}

// ---------------- GEMM: C[m][n] = sum_k A[m][k]*Bt[n][k], 128x128x64 tiles ----------------
// MODE 0: qkv (A=xn_t M=8192, Bt=qkv_w N=1536) -> scatter q_s/k_s/vT (+bias)
// MODE 1: ckv (A=ctx_bf M=640, Bt=ckv_w N=1024) -> scatter k_s/vT (+bias), skip pad rows
// MODE 2: proj (A=proj_w M=512, Bt=at_s N=8192) -> out = acc + bias[row] + x (residual)
template <int MODE>
__global__ __launch_bounds__(256) void gemm_bt_k(const unsigned short* __restrict__ A,
                                                 const unsigned short* __restrict__ Bt,
                                                 int M, int N, int K,
                                                 const float* __restrict__ bias,
                                                 unsigned short* __restrict__ out_q,
                                                 unsigned short* __restrict__ out_k,
                                                 unsigned short* __restrict__ out_v,
                                                 const float* __restrict__ xres,
                                                 float* __restrict__ outf) {
  __shared__ unsigned short As[128 * 64];
  __shared__ unsigned short Bs[128 * 64];
  const int tid = threadIdx.x;
  const int wid = tid >> 6, lane = tid & 63;
  const int lr = lane & 15, lg = lane >> 4;
  const int ntn = N >> 7;
  const int tm = blockIdx.x / ntn, tn = blockIdx.x - tm * ntn;
  const int m0 = tm << 7, n0 = tn << 7;
  const int wr = wid >> 1, wc = wid & 1;
  f32x4 acc[4][4] = {};
  const int nkt = K >> 6;
  for (int kt = 0; kt < nkt; ++kt) {
    const int k0 = kt << 6;
#pragma unroll
    for (int i = 0; i < 4; ++i) {
      int cA = i * 256 + tid;
      const unsigned short* srcA = A + (size_t)(m0 + (cA >> 3)) * K + k0 + (cA & 7) * 8;
      GLD_LDS16(srcA, As + (size_t)(i * 256 + wid * 64) * 8);
    }
#pragma unroll
    for (int i = 0; i < 4; ++i) {
      int cB = i * 256 + tid;
      const unsigned short* srcB = Bt + (size_t)(n0 + (cB >> 3)) * K + k0 + (cB & 7) * 8;
      GLD_LDS16(srcB, Bs + (size_t)(i * 256 + wid * 64) * 8);
    }
    __syncthreads();
#pragma unroll
    for (int ks = 0; ks < 2; ++ks) {
      bf16x8 af[4], bf[4];
#pragma unroll
      for (int mi = 0; mi < 4; ++mi)
        af[mi] = *(const bf16x8*)&As[(wr * 64 + mi * 16 + lr) * 64 + ks * 32 + lg * 8];
#pragma unroll
      for (int nj = 0; nj < 4; ++nj)
        bf[nj] = *(const bf16x8*)&Bs[(wc * 64 + nj * 16 + lr) * 64 + ks * 32 + lg * 8];
#pragma unroll
      for (int mi = 0; mi < 4; ++mi)
#pragma unroll
        for (int nj = 0; nj < 4; ++nj)
          acc[mi][nj] = __builtin_amdgcn_mfma_f32_16x16x32_bf16(af[mi], bf[nj], acc[mi][nj], 0, 0, 0);
    }
    __syncthreads();
  }
#pragma unroll
  for (int mi = 0; mi < 4; ++mi) {
#pragma unroll
    for (int nj = 0; nj < 4; ++nj) {
#pragma unroll
      for (int r = 0; r < 4; ++r) {
        int row = m0 + wr * 64 + mi * 16 + lg * 4 + r;
        int col = n0 + wc * 64 + nj * 16 + lr;
        float v = acc[mi][nj][r];
        if (MODE == 0) {
          v += bias[col];
          unsigned short hv = f2bf(v);
          int bb = row >> 10, qi = row & 1023;
          int which = col >> 9, head = (col >> 6) & 7, d = col & 63;
          size_t bh = (size_t)bb * HEADS_ + head;
          if (which == 0)      out_q[(bh * HW_ + qi) * HD_ + d] = hv;
          else if (which == 1) out_k[(bh * KVP_ + (L_ + qi)) * HD_ + d] = hv;
          else                 out_v[(bh * HD_ + d) * KVP_ + (L_ + qi)] = hv;
        } else if (MODE == 1) {
          int bb = row / LP_, l = row - bb * LP_;
          if (l < L_) {
            v += bias[col];
            unsigned short hv = f2bf(v);
            int which = col >> 9, head = (col >> 6) & 7, d = col & 63;
            size_t bh = (size_t)bb * HEADS_ + head;
            if (which == 0) out_k[(bh * KVP_ + l) * HD_ + d] = hv;
            else            out_v[(bh * HD_ + d) * KVP_ + l] = hv;
          }
        } else {
          size_t idx = (size_t)(col >> 10) * (DIM_ * HW_) + (size_t)row * HW_ + (col & 1023);
          outf[idx] = v + bias[row] + xres[idx];
        }
      }
    }
  }
}

// ---------------- flash attention ----------------
// grid = 64 (b,head) * 16 qchunks; block = 4 waves; wave = 16 q rows.
__global__ __launch_bounds__(256) void attn_k(const unsigned short* __restrict__ q_s,
                                              const unsigned short* __restrict__ k_s,
                                              const unsigned short* __restrict__ vT,
                                              unsigned short* __restrict__ at_s) {
  __shared__ unsigned short P[4][16 * 32];
  const int tid = threadIdx.x;
  const int wid = tid >> 6, lane = tid & 63;
  const int lr = lane & 15, lg = lane >> 4;
  const int bh = blockIdx.x >> 4;
  const int qt = blockIdx.x & 15;
  const int q0 = qt * 64 + wid * 16;
  const unsigned short* qp = q_s + (size_t)bh * HW_ * HD_;
  const unsigned short* kp = k_s + (size_t)bh * KVP_ * HD_;
  const unsigned short* vp = vT + (size_t)bh * HD_ * KVP_;
  unsigned short* Pw = P[wid];

  bf16x8 qf[2];
#pragma unroll
  for (int ks = 0; ks < 2; ++ks)
    qf[ks] = *(const bf16x8*)&qp[(size_t)(q0 + lr) * HD_ + ks * 32 + lg * 8];

  f32x4 acc_o[4] = {};
  float mrun[4], lrun[4];
#pragma unroll
  for (int r = 0; r < 4; ++r) { mrun[r] = -INFINITY; lrun[r] = 0.f; }

  for (int kt = 0; kt < 35; ++kt) {
    const int k0 = kt * 32;
    f32x4 s[2] = {};
#pragma unroll
    for (int ks = 0; ks < 2; ++ks)
#pragma unroll
      for (int nj = 0; nj < 2; ++nj) {
        bf16x8 kf = *(const bf16x8*)&kp[(size_t)(k0 + nj * 16 + lr) * HD_ + ks * 32 + lg * 8];
        s[nj] = __builtin_amdgcn_mfma_f32_16x16x32_bf16(qf[ks], kf, s[nj], 0, 0, 0);
      }
    // scale + tail mask
#pragma unroll
    for (int nj = 0; nj < 2; ++nj) {
      int ki = k0 + nj * 16 + lr;
      bool valid = ki < KV_;
#pragma unroll
      for (int r = 0; r < 4; ++r)
        s[nj][r] = valid ? s[nj][r] * 0.125f : -INFINITY;
    }
    float mx[4];
#pragma unroll
    for (int r = 0; r < 4; ++r) mx[r] = fmaxf(s[0][r], s[1][r]);
#pragma unroll
    for (int off = 8; off >= 1; off >>= 1)
#pragma unroll
      for (int r = 0; r < 4; ++r) mx[r] = fmaxf(mx[r], __shfl_xor(mx[r], off, 16));
    float alpha[4], rs[4];
#pragma unroll
    for (int r = 0; r < 4; ++r) {
      float mn = fmaxf(mrun[r], mx[r]);
      alpha[r] = exp2f((mrun[r] - mn) * LOG2E);
      mrun[r] = mn;
      rs[r] = 0.f;
    }
#pragma unroll
    for (int nj = 0; nj < 2; ++nj)
#pragma unroll
      for (int r = 0; r < 4; ++r) {
        float p = exp2f((s[nj][r] - mrun[r]) * LOG2E);
        s[nj][r] = p;
        rs[r] += p;
      }
#pragma unroll
    for (int off = 8; off >= 1; off >>= 1)
#pragma unroll
      for (int r = 0; r < 4; ++r) rs[r] += __shfl_xor(rs[r], off, 16);
#pragma unroll
    for (int r = 0; r < 4; ++r) lrun[r] = lrun[r] * alpha[r] + rs[r];
#pragma unroll
    for (int nj2 = 0; nj2 < 4; ++nj2)
#pragma unroll
      for (int r = 0; r < 4; ++r) acc_o[nj2][r] *= alpha[r];
    // P (D-frag layout) -> LDS -> A-frag layout
#pragma unroll
    for (int nj = 0; nj < 2; ++nj)
#pragma unroll
      for (int r = 0; r < 4; ++r)
        Pw[(lg * 4 + r) * 32 + nj * 16 + lr] = f2bf(s[nj][r]);
    asm volatile("s_waitcnt lgkmcnt(0)" ::: "memory");
    __builtin_amdgcn_sched_barrier(0);
    bf16x8 pa = *(const bf16x8*)&Pw[lr * 32 + lg * 8];
    __builtin_amdgcn_sched_barrier(0);
#pragma unroll
    for (int nj2 = 0; nj2 < 4; ++nj2) {
      bf16x8 vf = *(const bf16x8*)&vp[(size_t)(nj2 * 16 + lr) * KVP_ + k0 + lg * 8];
      acc_o[nj2] = __builtin_amdgcn_mfma_f32_16x16x32_bf16(pa, vf, acc_o[nj2], 0, 0, 0);
    }
    __builtin_amdgcn_sched_barrier(0);
  }
  const int bb = bh >> 3, head = bh & 7;
#pragma unroll
  for (int r = 0; r < 4; ++r) {
    float inv = 1.f / lrun[r];
    int qi = q0 + lg * 4 + r;
#pragma unroll
    for (int nj2 = 0; nj2 < 4; ++nj2)
      at_s[((size_t)bb * HW_ + qi) * DIM_ + head * HD_ + nj2 * 16 + lr] = f2bf(acc_o[nj2][r] * inv);
  }
}

extern "C" void kernel_launch(void* const* d_in, const int* in_sizes, int n_in,
                              void* d_out, int out_size, void* d_ws, size_t ws_size,
                              hipStream_t stream) {
  (void)in_sizes; (void)n_in; (void)out_size; (void)ws_size;
  const float* x      = (const float*)d_in[0];
  const float* ctx    = (const float*)d_in[1];
  const float* gng    = (const float*)d_in[2];
  const float* gnb    = (const float*)d_in[3];
  const float* qkv_w  = (const float*)d_in[4];
  const float* qkv_b  = (const float*)d_in[5];
  const float* ckv_w  = (const float*)d_in[6];
  const float* ckv_b  = (const float*)d_in[7];
  const float* proj_w = (const float*)d_in[8];
  const float* proj_b = (const float*)d_in[9];
  float* out = (float*)d_out;

  char* ws = (char*)d_ws;
  size_t off = 0;
  auto alloc = [&](size_t bytes) {
    char* p = ws + off;
    off = (off + bytes + 255) & ~(size_t)255;
    return p;
  };
  unsigned short* xn_t    = (unsigned short*)alloc((size_t)B_ * HW_ * DIM_ * 2);
  unsigned short* ctx_bf  = (unsigned short*)alloc((size_t)B_ * LP_ * CTX_ * 2);
  unsigned short* qkvw_bf = (unsigned short*)alloc((size_t)3 * DIM_ * DIM_ * 2);
  unsigned short* ckvw_bf = (unsigned short*)alloc((size_t)2 * DIM_ * CTX_ * 2);
  unsigned short* projw_bf= (unsigned short*)alloc((size_t)DIM_ * DIM_ * 2);
  unsigned short* q_s     = (unsigned short*)alloc((size_t)64 * HW_ * HD_ * 2);
  unsigned short* k_s     = (unsigned short*)alloc((size_t)64 * KVP_ * HD_ * 2);
  unsigned short* vT      = (unsigned short*)alloc((size_t)64 * HD_ * KVP_ * 2);
  unsigned short* at_s    = (unsigned short*)alloc((size_t)B_ * HW_ * DIM_ * 2);

  conv_bf16_k<<<768, 256, 0, stream>>>(qkv_w, qkvw_bf, 3 * DIM_ * DIM_ / 4);
  conv_bf16_k<<<768, 256, 0, stream>>>(ckv_w, ckvw_bf, 2 * DIM_ * CTX_ / 4);
  conv_bf16_k<<<256, 256, 0, stream>>>(proj_w, projw_bf, DIM_ * DIM_ / 4);
  conv_ctx_k<<<480, 256, 0, stream>>>(ctx, ctx_bf);
  gnorm_k<<<256, 256, 0, stream>>>(x, gng, gnb, xn_t);
  pad_zero_k<<<304, 256, 0, stream>>>(k_s, vT);
  gemm_bt_k<0><<<768, 256, 0, stream>>>(xn_t, qkvw_bf, 8192, 1536, 512, qkv_b,
                                        q_s, k_s, vT, nullptr, nullptr);
  gemm_bt_k<1><<<40, 256, 0, stream>>>(ctx_bf, ckvw_bf, 640, 1024, 768, ckv_b,
                                       nullptr, k_s, vT, nullptr, nullptr);
  attn_k<<<1024, 256, 0, stream>>>(q_s, k_s, vT, at_s);
  gemm_bt_k<2><<<256, 256, 0, stream>>>(projw_bf, at_s, 512, 8192, 512, proj_b,
                                        nullptr, nullptr, nullptr, x, out);
}